// Round 13
// baseline (189.698 us; speedup 1.0000x reference)
//
#include <hip/hip_runtime.h>
#include <hip/hip_bf16.h>
#include <stdint.h>

#define DEV __device__ __forceinline__

using f32x4  = __attribute__((ext_vector_type(4))) float;
using bf16x8 = __attribute__((ext_vector_type(8))) short;
using u16x4  = __attribute__((ext_vector_type(4))) unsigned short;
using u16x8  = __attribute__((ext_vector_type(8))) unsigned short;
using u32x4  = __attribute__((ext_vector_type(4))) uint32_t;

DEV uint16_t f2b(float f) {
  uint32_t u = __builtin_bit_cast(uint32_t, f);
  uint32_t r = u + 0x7FFFu + ((u >> 16) & 1u);
  return (uint16_t)(r >> 16);
}
DEV float b2f(uint16_t h) {
  return __builtin_bit_cast(float, (uint32_t)h << 16);
}

DEV uint32_t cvtpk(float lo, float hi) {
  uint32_t r;
  asm("v_cvt_pk_bf16_f32 %0, %1, %2" : "=v"(r) : "v"(lo), "v"(hi));
  return r;
}

DEV void gload16(const void* g, void* l) {
  __builtin_amdgcn_global_load_lds((__attribute__((address_space(1))) void*)g,
                                   (__attribute__((address_space(3))) void*)l,
                                   16, 0, 0);
}

// All LDS tiles here have 128-byte rows; XOR-swizzle bits 4..6 by (row&7).
DEV bf16x8 ldsfrag(const uint16_t* base, int row, int cb) {
  int b = row * 128 + (cb ^ ((row & 7) << 4));
  return *(const bf16x8*)((const uint8_t*)base + b);
}

DEV f32x4 MFMA(bf16x8 a, bf16x8 b, f32x4 c) {
  return __builtin_amdgcn_mfma_f32_16x16x32_bf16(a, b, c, 0, 0, 0);
}

// ---------------- fp32 -> bf16 convert, all 3 inputs in one launch ----------
__global__ void k_convert3(const float* __restrict__ A0, const float* __restrict__ A1,
                           const float* __restrict__ A2, uint16_t* __restrict__ O0,
                           uint16_t* __restrict__ O1, uint16_t* __restrict__ O2) {
  const int z = blockIdx.z;
  const float* in = (z == 0) ? A0 : (z == 1) ? A1 : A2;
  uint16_t* out = (z == 0) ? O0 : (z == 1) ? O1 : O2;
  int i = blockIdx.x * blockDim.x + threadIdx.x;
  int stride = gridDim.x * blockDim.x;
  for (; i < 1048576; i += stride) {
    f32x4 v = ((const f32x4*)in)[i];
    u16x4 o;
    o[0] = f2b(v[0]); o[1] = f2b(v[1]); o[2] = f2b(v[2]); o[3] = f2b(v[3]);
    ((u16x4*)out)[i] = o;
  }
}

// ---------------- all 4 weights: W [k][n] fp32 -> Wt [n][k] bf16 (x scale) ----
__global__ void k_wtrans4(const float* __restrict__ W0, const float* __restrict__ W1,
                          const float* __restrict__ W2, const float* __restrict__ W3,
                          uint16_t* __restrict__ WtBase, float scale0) {
  __shared__ float t[32][33];
  const int z = blockIdx.z;
  const float* W = (z == 0) ? W0 : (z == 1) ? W1 : (z == 2) ? W2 : W3;
  const float scale = (z == 0) ? scale0 : 1.0f;
  uint16_t* Wt = WtBase + (size_t)z * 262144;
  int tx = threadIdx.x, ty = threadIdx.y;
  int n0 = blockIdx.x * 32, k0 = blockIdx.y * 32;
#pragma unroll
  for (int i = 0; i < 4; ++i)
    t[ty + 8 * i][tx] = W[(size_t)(k0 + ty + 8 * i) * 512 + n0 + tx];
  __syncthreads();
#pragma unroll
  for (int i = 0; i < 4; ++i)
    Wt[(size_t)(n0 + ty + 8 * i) * 512 + k0 + tx] = f2b(t[tx][ty + 8 * i] * scale);
}

// ---------------- GEMM staging helper (bf16, 128B rows) ----------------
DEV void stage_gemm(const uint8_t* Ab, const uint8_t* Bb, int m0, int n0, int kt,
                    uint16_t* As, uint16_t* Bs, int wid, int l8, int cb0) {
#pragma unroll
  for (int i = 0; i < 4; ++i) {
    int inst = wid + i * 4;
    int row = inst * 8 + l8;
    int cbs = cb0 ^ ((row & 7) << 4);
    gload16(Ab + (size_t)(m0 + row) * 1024 + kt * 128 + cbs, (uint8_t*)As + inst * 1024);
  }
#pragma unroll
  for (int i = 0; i < 2; ++i) {
    int inst = wid + i * 4;
    int row = inst * 8 + l8;
    int cbs = cb0 ^ ((row & 7) << 4);
    gload16(Bb + (size_t)(n0 + row) * 1024 + kt * 128 + cbs, (uint8_t*)Bs + inst * 1024);
  }
}

// ---------------- QKV GEMM: bf16 A[8192x512] x Wt[z]^T -> bf16 out[z] --------
// z<2: out [BH][S][64]; z==2: out transposed [BH][64][S]
__global__ __launch_bounds__(256) void k_gemm_qkv(const uint16_t* __restrict__ A0,
                                                  const uint16_t* __restrict__ A1,
                                                  const uint16_t* __restrict__ A2,
                                                  const uint16_t* __restrict__ WtBase,
                                                  uint16_t* __restrict__ O0,
                                                  uint16_t* __restrict__ O1,
                                                  uint16_t* __restrict__ O2, int zbase) {
  __shared__ uint16_t As[2][8192];
  __shared__ uint16_t Bs[2][4096];
  const int z = blockIdx.z + zbase;
  const uint16_t* A = (z == 0) ? A0 : (z == 1) ? A1 : A2;
  uint16_t* out = (z == 0) ? O0 : (z == 1) ? O1 : O2;
  const uint8_t* Ab = (const uint8_t*)A;
  const uint8_t* Bb = (const uint8_t*)(WtBase + (size_t)z * 262144);
  const int tid = threadIdx.x, lane = tid & 63, wid = tid >> 6;
  const int g = lane >> 4, c16 = lane & 15;
  const int wm = wid & 1, wn = wid >> 1;
  const int m0 = blockIdx.x * 128, n0 = blockIdx.y * 64;
  const int l8 = lane >> 3, cb0 = (lane & 7) << 4;

  f32x4 acc[4][2] = {};

  stage_gemm(Ab, Bb, m0, n0, 0, As[0], Bs[0], wid, l8, cb0);
  __syncthreads();

  for (int kt = 0; kt < 8; ++kt) {
    const int cur = kt & 1;
    if (kt < 7)
      stage_gemm(Ab, Bb, m0, n0, kt + 1, As[cur ^ 1], Bs[cur ^ 1], wid, l8, cb0);
    const uint16_t* Ac = As[cur];
    const uint16_t* Bc = Bs[cur];
#pragma unroll
    for (int ks = 0; ks < 2; ++ks) {
      int cb = ks * 64 + (g << 4);
      bf16x8 af[4], bfr[2];
#pragma unroll
      for (int mi = 0; mi < 4; ++mi) af[mi] = ldsfrag(Ac, wm * 64 + mi * 16 + c16, cb);
#pragma unroll
      for (int ni = 0; ni < 2; ++ni) bfr[ni] = ldsfrag(Bc, wn * 32 + ni * 16 + c16, cb);
#pragma unroll
      for (int mi = 0; mi < 4; ++mi)
#pragma unroll
        for (int ni = 0; ni < 2; ++ni)
          acc[mi][ni] = MFMA(af[mi], bfr[ni], acc[mi][ni]);
    }
    __syncthreads();
  }

  const int lm = g * 4;
  if (z != 2) {
#pragma unroll
    for (int mi = 0; mi < 4; ++mi)
#pragma unroll
      for (int ni = 0; ni < 2; ++ni)
#pragma unroll
        for (int r = 0; r < 4; ++r) {
          int m = m0 + wm * 64 + mi * 16 + lm + r;
          int n = n0 + wn * 32 + ni * 16 + c16;
          size_t a = (size_t)((m >> 11) * 8 + (n >> 6)) * 131072 + (size_t)(m & 2047) * 64 + (n & 63);
          out[a] = f2b(acc[mi][ni][r]);
        }
  } else {
#pragma unroll
    for (int mi = 0; mi < 4; ++mi)
#pragma unroll
      for (int ni = 0; ni < 2; ++ni) {
        int m = m0 + wm * 64 + mi * 16 + lm;
        int n = n0 + wn * 32 + ni * 16 + c16;
        u16x4 w;
#pragma unroll
        for (int r = 0; r < 4; ++r) w[r] = f2b(acc[mi][ni][r]);
        size_t a = (size_t)((m >> 11) * 8 + (n >> 6)) * 131072 + (size_t)(n & 63) * 2048 + (m & 2047);
        *(u16x4*)(out + a) = w;
      }
  }
}

// ---------------- FC GEMM: bf16 C[8192x512] = Ctx bf16 x WtF^T ----------------
__global__ __launch_bounds__(256) void k_gemm_fc(const uint16_t* __restrict__ A,
                                                 const uint16_t* __restrict__ Bt,
                                                 uint16_t* __restrict__ out) {
  __shared__ uint16_t As[2][8192];
  __shared__ uint16_t Bs[2][4096];
  const int tid = threadIdx.x, lane = tid & 63, wid = tid >> 6;
  const int g = lane >> 4, c16 = lane & 15;
  const int wm = wid & 1, wn = wid >> 1;
  const int m0 = blockIdx.x * 128, n0 = blockIdx.y * 64;
  const uint8_t* Ab = (const uint8_t*)A;
  const uint8_t* Bb = (const uint8_t*)Bt;
  const int l8 = lane >> 3, cb0 = (lane & 7) << 4;

  f32x4 acc[4][2] = {};

  stage_gemm(Ab, Bb, m0, n0, 0, As[0], Bs[0], wid, l8, cb0);
  __syncthreads();

  for (int kt = 0; kt < 8; ++kt) {
    const int cur = kt & 1;
    if (kt < 7)
      stage_gemm(Ab, Bb, m0, n0, kt + 1, As[cur ^ 1], Bs[cur ^ 1], wid, l8, cb0);
    const uint16_t* Ac = As[cur];
    const uint16_t* Bc = Bs[cur];
#pragma unroll
    for (int ks = 0; ks < 2; ++ks) {
      int cb = ks * 64 + (g << 4);
      bf16x8 af[4], bfr[2];
#pragma unroll
      for (int mi = 0; mi < 4; ++mi) af[mi] = ldsfrag(Ac, wm * 64 + mi * 16 + c16, cb);
#pragma unroll
      for (int ni = 0; ni < 2; ++ni) bfr[ni] = ldsfrag(Bc, wn * 32 + ni * 16 + c16, cb);
#pragma unroll
      for (int mi = 0; mi < 4; ++mi)
#pragma unroll
        for (int ni = 0; ni < 2; ++ni)
          acc[mi][ni] = MFMA(af[mi], bfr[ni], acc[mi][ni]);
    }
    __syncthreads();
  }

  const int lm = g * 4;
#pragma unroll
  for (int mi = 0; mi < 4; ++mi)
#pragma unroll
    for (int ni = 0; ni < 2; ++ni)
#pragma unroll
      for (int r = 0; r < 4; ++r) {
        int m = m0 + wm * 64 + mi * 16 + lm + r;
        int n = n0 + wn * 32 + ni * 16 + c16;
        out[(size_t)m * 512 + n] = f2b(acc[mi][ni][r]);
      }
}

// ---------------- Flash attention, causal, QBLK=64, NO LDS STAGING ----------
// K/V MFMA fragments are wave-invariant -> read them straight from global
// (L1/L2-resident tiles) instead of staging through LDS 4x redundantly.
// No __syncthreads in the main loop; waves fully decoupled.
// Shift-free softmax p=exp2(s); row-sum via ones-MFMA.
__global__ __launch_bounds__(256) void k_attn(const uint16_t* __restrict__ qg,
                                              const uint16_t* __restrict__ kg,
                                              const uint16_t* __restrict__ vtg,
                                              uint16_t* __restrict__ ctxg) {
  const int x = blockIdx.x, bh = blockIdx.y;
  const int gx = (x & 1) ? (x >> 1) : 31 - (x >> 1);
  const int qi = ((bh >> 3) & 1) ? 31 - gx : gx;

  const int tid = threadIdx.x, lane = tid & 63, wid = tid >> 6;
  const int g = lane >> 4, qcol = lane & 15;
  __shared__ uint16_t smem[4][1024];  // per-wave epilogue transpose only (8KB)
  const uint8_t* qb = (const uint8_t*)(qg + (size_t)bh * 131072);
  const uint8_t* kb = (const uint8_t*)(kg + (size_t)bh * 131072);
  const uint8_t* vb = (const uint8_t*)(vtg + (size_t)bh * 131072);
  const int qrow_w = qi * 64 + wid * 16;  // wave's first q row

  // Q fragments straight from global (L2-resident)
  bf16x8 qf[2];
  {
    const uint8_t* qrow = qb + (size_t)(qrow_w + qcol) * 128;
    qf[0] = *(const bf16x8*)(qrow + (g << 4));
    qf[1] = *(const bf16x8*)(qrow + 64 + (g << 4));
  }

  // K global row-in-tile for each sf fragment (the perm trick), loop-invariant:
  // rho = sf*16+qcol -> s_loc = ((sf&1)<<5)|((qcol>>2)<<3)|((sf>>1)<<2)|(qcol&3)
  int srow[4];
#pragma unroll
  for (int sf = 0; sf < 4; ++sf)
    srow[sf] = ((sf & 1) << 5) | ((qcol >> 2) << 3) | ((sf >> 1) << 2) | (qcol & 3);

  // all-ones bf16 A-fragment for the row-sum MFMA
  bf16x8 ones;
#pragma unroll
  for (int j = 0; j < 8; ++j) ones[j] = (short)0x3F80;

  f32x4 oacc[4] = {};
  f32x4 lacc = {};
  const int nkt = qi + 1;

  for (int kt = 0; kt < nkt; ++kt) {
    // S^T = K * Q^T  (rows: permuted s, cols: q); K fragments direct from global
    f32x4 sacc[4] = {};
#pragma unroll
    for (int ks2 = 0; ks2 < 2; ++ks2) {
#pragma unroll
      for (int sf = 0; sf < 4; ++sf) {
        bf16x8 kf = *(const bf16x8*)(kb + (size_t)(kt * 64 + srow[sf]) * 128 +
                                     ks2 * 64 + (g << 4));
        sacc[sf] = MFMA(kf, qf[ks2], sacc[sf]);
      }
    }

    // causal mask (only the diagonal tile)
    if (kt * 64 + 63 > qrow_w) {
      int q_glob = qrow_w + qcol;
#pragma unroll
      for (int sf = 0; sf < 4; ++sf)
#pragma unroll
        for (int r = 0; r < 4; ++r) {
          int s_glob = kt * 64 + (((sf & 1) << 5) | (g << 3) | ((sf >> 1) << 2) | r);
          if (s_glob > q_glob) sacc[sf][r] = -1e30f;
        }
    }

    // p = exp2(s); shift-free (cancels in O/l)
    float p[4][4];
#pragma unroll
    for (int sf = 0; sf < 4; ++sf)
#pragma unroll
      for (int r = 0; r < 4; ++r) p[sf][r] = __builtin_amdgcn_exp2f(sacc[sf][r]);

    // O^T += V^T * P^T ; l += ones * P^T ; V fragments direct from global
#pragma unroll
    for (int ks = 0; ks < 2; ++ks) {
      u32x4 tv;
      tv[0] = cvtpk(p[ks][0], p[ks][1]);
      tv[1] = cvtpk(p[ks][2], p[ks][3]);
      tv[2] = cvtpk(p[2 + ks][0], p[2 + ks][1]);
      tv[3] = cvtpk(p[2 + ks][2], p[2 + ks][3]);
      bf16x8 pb = __builtin_bit_cast(bf16x8, tv);
      lacc = MFMA(ones, pb, lacc);
#pragma unroll
      for (int dkf = 0; dkf < 4; ++dkf) {
        bf16x8 vf = *(const bf16x8*)(vb + (size_t)(dkf * 16 + qcol) * 4096 +
                                     kt * 128 + ks * 64 + (g << 4));
        oacc[dkf] = MFMA(vf, pb, oacc[dkf]);
      }
    }
  }

  // epilogue: transpose O^T -> O via this wave's private LDS region (no barrier
  // needed: same-wave write->read, compiler inserts lgkmcnt waits).
  uint16_t* Os = smem[wid];
  {
    float iv = 1.f / lacc[0];
    int q_l = qcol;
#pragma unroll
    for (int dkf = 0; dkf < 4; ++dkf) {
      u16x4 w;
#pragma unroll
      for (int r = 0; r < 4; ++r) w[r] = f2b(oacc[dkf][r] * iv);
      int dkb = dkf * 32 + g * 8;
      int bo = q_l * 128 + (dkb ^ ((q_l & 7) << 4));
      *(u16x4*)((uint8_t*)Os + bo) = w;
    }
  }
  const int bb = bh >> 3, hh = bh & 7;
#pragma unroll
  for (int j = 0; j < 2; ++j) {
    int lin = j * 1024 + lane * 16;
    int q_l = lin >> 7;
    int cb = lin & 127;
    int bo = q_l * 128 + (cb ^ ((q_l & 7) << 4));
    bf16x8 val = *(const bf16x8*)((const uint8_t*)Os + bo);
    size_t ga = (size_t)(bb * 2048 + qrow_w + q_l) * 512 + hh * 64 + (cb >> 1);
    *(bf16x8*)(ctxg + ga) = val;
  }
}

// ---------------- residual + LayerNorm (fc in bf16) ----------------
__global__ __launch_bounds__(256) void k_ln(const uint16_t* __restrict__ fc,
                                            const float* __restrict__ resid,
                                            const float* __restrict__ gamma,
                                            const float* __restrict__ beta,
                                            float* __restrict__ out) {
  int row = blockIdx.x * 4 + (threadIdx.x >> 6);
  int lane = threadIdx.x & 63;
  const uint16_t* fr = fc + (size_t)row * 512 + lane * 8;
  const float* rr = resid + (size_t)row * 512 + lane * 8;
  u16x8 fv = *(const u16x8*)fr;
  f32x4 c = *(const f32x4*)rr;
  f32x4 d = *(const f32x4*)(rr + 4);
  float y[8];
#pragma unroll
  for (int j = 0; j < 4; ++j) { y[j] = b2f(fv[j]) + c[j]; y[4 + j] = b2f(fv[4 + j]) + d[j]; }
  float s = 0.f, s2 = 0.f;
#pragma unroll
  for (int j = 0; j < 8; ++j) { s += y[j]; s2 = fmaf(y[j], y[j], s2); }
#pragma unroll
  for (int off = 1; off < 64; off <<= 1) {
    s += __shfl_xor(s, off);
    s2 += __shfl_xor(s2, off);
  }
  float mean = s * (1.f / 512.f);
  float var = s2 * (1.f / 512.f) - mean * mean;
  float rstd = rsqrtf(var + 1e-5f);
  f32x4 o0, o1;
#pragma unroll
  for (int j = 0; j < 4; ++j) {
    o0[j] = (y[j] - mean) * rstd * gamma[lane * 8 + j] + beta[lane * 8 + j];
    o1[j] = (y[4 + j] - mean) * rstd * gamma[lane * 8 + 4 + j] + beta[lane * 8 + 4 + j];
  }
  float* op = out + (size_t)row * 512 + lane * 8;
  *(f32x4*)op = o0;
  *(f32x4*)(op + 4) = o1;
}

extern "C" void kernel_launch(void* const* d_in, const int* in_sizes, int n_in,
                              void* d_out, int out_size, void* d_ws, size_t ws_size,
                              hipStream_t stream) {
  const float* inQ = (const float*)d_in[0];
  const float* inK = (const float*)d_in[1];
  const float* inV = (const float*)d_in[2];
  const float* Wq = (const float*)d_in[4];
  const float* Wk = (const float*)d_in[5];
  const float* Wv = (const float*)d_in[6];
  const float* Wfc = (const float*)d_in[7];
  const float* gamma = (const float*)d_in[8];
  const float* beta = (const float*)d_in[9];
  uint8_t* ws = (uint8_t*)d_ws;
  const size_t MB = 1048576;

  uint16_t* Wt  = (uint16_t*)(ws + 0);          // 4 x 512 KB
  uint16_t* Xb0 = (uint16_t*)(ws + 2 * MB);     // bf16 activations, 8 MB each
  uint16_t* Xb1 = (uint16_t*)(ws + 10 * MB);
  uint16_t* Xb2 = (uint16_t*)(ws + 18 * MB);
  const bool fused = ws_size >= 52 * MB;

  uint16_t *Qb, *Kb, *Vtb, *Ctx, *Fc;
  if (fused) {
    Qb  = (uint16_t*)(ws + 26 * MB);
    Kb  = (uint16_t*)(ws + 34 * MB);
    Vtb = (uint16_t*)(ws + 42 * MB);
    Ctx = (uint16_t*)(ws + 2 * MB);   // aliases Xb0 (dead after QKV gemm)
    Fc  = (uint16_t*)(ws + 10 * MB);  // aliases Xb1 (dead)
  } else {
    Qb  = (uint16_t*)(ws + 26 * MB);
    Kb  = (uint16_t*)(ws + 34 * MB);
    Vtb = (uint16_t*)(ws + 2 * MB);   // aliases Xb0 (dead after gemm-Q)
    Ctx = (uint16_t*)(ws + 10 * MB);  // aliases Xb1 (dead after gemm-K)
    Fc  = (uint16_t*)(ws + 18 * MB);  // aliases Xb2 (dead by FC time)
  }
  float* out = (float*)d_out;

  dim3 b256(256);
  dim3 tb(32, 8), tg4(16, 16, 4);
  // fold attention scale * log2(e) into W_Q
  k_wtrans4<<<tg4, tb, 0, stream>>>(Wq, Wk, Wv, Wfc, Wt, 0.18033688011112042f);

  dim3 cg(1024, 1, 3);
  k_convert3<<<cg, b256, 0, stream>>>(inQ, inK, inV, Xb0, Xb1, Xb2);

  if (fused) {
    dim3 gq(64, 8, 3);
    k_gemm_qkv<<<gq, b256, 0, stream>>>(Xb0, Xb1, Xb2, Wt, Qb, Kb, Vtb, 0);
  } else {
    dim3 gq(64, 8, 1);
    k_gemm_qkv<<<gq, b256, 0, stream>>>(Xb0, Xb1, Xb2, Wt, Qb, Kb, Vtb, 0);
    k_gemm_qkv<<<gq, b256, 0, stream>>>(Xb0, Xb1, Xb2, Wt, Qb, Kb, Vtb, 1);
    k_gemm_qkv<<<gq, b256, 0, stream>>>(Xb0, Xb1, Xb2, Wt, Qb, Kb, Vtb, 2);
  }

  dim3 ag(32, 32);
  k_attn<<<ag, b256, 0, stream>>>(Qb, Kb, Vtb, Ctx);

  dim3 gg(64, 8);
  k_gemm_fc<<<gg, b256, 0, stream>>>(Ctx, Wt + 3 * 262144, Fc);
  k_ln<<<2048, b256, 0, stream>>>(Fc, inQ, gamma, beta, out);
}

// Round 14
// 91.482 us; speedup vs baseline: 2.0736x; 2.0736x over previous
//
#include <hip/hip_runtime.h>
#include <hip/hip_bf16.h>
#include <stdint.h>

#define DEV __device__ __forceinline__

using f32x4  = __attribute__((ext_vector_type(4))) float;
using bf16x8 = __attribute__((ext_vector_type(8))) short;
using u16x4  = __attribute__((ext_vector_type(4))) unsigned short;
using u16x8  = __attribute__((ext_vector_type(8))) unsigned short;
using u32x4  = __attribute__((ext_vector_type(4))) uint32_t;

DEV uint16_t f2b(float f) {
  uint32_t u = __builtin_bit_cast(uint32_t, f);
  uint32_t r = u + 0x7FFFu + ((u >> 16) & 1u);
  return (uint16_t)(r >> 16);
}
DEV float b2f(uint16_t h) {
  return __builtin_bit_cast(float, (uint32_t)h << 16);
}

DEV uint32_t cvtpk(float lo, float hi) {
  uint32_t r;
  asm("v_cvt_pk_bf16_f32 %0, %1, %2" : "=v"(r) : "v"(lo), "v"(hi));
  return r;
}

DEV void gload16(const void* g, void* l) {
  __builtin_amdgcn_global_load_lds((__attribute__((address_space(1))) void*)g,
                                   (__attribute__((address_space(3))) void*)l,
                                   16, 0, 0);
}

// bf16 LDS tiles have 128-byte rows; XOR-swizzle bits 4..6 by (row&7).
DEV bf16x8 ldsfrag(const uint16_t* base, int row, int cb) {
  int b = row * 128 + (cb ^ ((row & 7) << 4));
  return *(const bf16x8*)((const uint8_t*)base + b);
}

DEV f32x4 MFMA(bf16x8 a, bf16x8 b, f32x4 c) {
  return __builtin_amdgcn_mfma_f32_16x16x32_bf16(a, b, c, 0, 0, 0);
}

// ---------------- all 4 weights: W [k][n] fp32 -> Wt [n][k] bf16 (x scale) ----
__global__ void k_wtrans4(const float* __restrict__ W0, const float* __restrict__ W1,
                          const float* __restrict__ W2, const float* __restrict__ W3,
                          uint16_t* __restrict__ WtBase, float scale0) {
  __shared__ float t[32][33];
  const int z = blockIdx.z;
  const float* W = (z == 0) ? W0 : (z == 1) ? W1 : (z == 2) ? W2 : W3;
  const float scale = (z == 0) ? scale0 : 1.0f;
  uint16_t* Wt = WtBase + (size_t)z * 262144;
  int tx = threadIdx.x, ty = threadIdx.y;
  int n0 = blockIdx.x * 32, k0 = blockIdx.y * 32;
#pragma unroll
  for (int i = 0; i < 4; ++i)
    t[ty + 8 * i][tx] = W[(size_t)(k0 + ty + 8 * i) * 512 + n0 + tx];
  __syncthreads();
#pragma unroll
  for (int i = 0; i < 4; ++i)
    Wt[(size_t)(n0 + ty + 8 * i) * 512 + k0 + tx] = f2b(t[tx][ty + 8 * i] * scale);
}

// ---------------- bf16 GEMM staging helper (128B rows) ----------------
DEV void stage_gemm(const uint8_t* Ab, const uint8_t* Bb, int m0, int n0, int kt,
                    uint16_t* As, uint16_t* Bs, int wid, int l8, int cb0) {
#pragma unroll
  for (int i = 0; i < 4; ++i) {
    int inst = wid + i * 4;
    int row = inst * 8 + l8;
    int cbs = cb0 ^ ((row & 7) << 4);
    gload16(Ab + (size_t)(m0 + row) * 1024 + kt * 128 + cbs, (uint8_t*)As + inst * 1024);
  }
#pragma unroll
  for (int i = 0; i < 2; ++i) {
    int inst = wid + i * 4;
    int row = inst * 8 + l8;
    int cbs = cb0 ^ ((row & 7) << 4);
    gload16(Bb + (size_t)(n0 + row) * 1024 + kt * 128 + cbs, (uint8_t*)Bs + inst * 1024);
  }
}

// ---------------- B-only staging (weights) ----------------
DEV void stageB(const uint8_t* Bb, int n0, int kt, uint16_t* Bs, int wid, int l8, int cb0) {
#pragma unroll
  for (int i = 0; i < 2; ++i) {
    int inst = wid + i * 4;
    int row = inst * 8 + l8;
    int cbs = cb0 ^ ((row & 7) << 4);
    gload16(Bb + (size_t)(n0 + row) * 1024 + kt * 128 + cbs, (uint8_t*)Bs + inst * 1024);
  }
}

// ---------------- fp32 A staging: [128 rows][256B], 16B-chunk XOR swizzle ----
// Linear LDS dest + inverse-swizzled global source (chunk ^= row&15).
DEV void stageA32(const uint8_t* Ab, int m0, int kt, uint8_t* Albuf, int wid, int lane) {
#pragma unroll
  for (int i = 0; i < 8; ++i) {
    int inst = wid + i * 4;
    int row = inst * 4 + (lane >> 4);
    int csrc = (lane & 15) ^ (row & 15);
    gload16(Ab + (size_t)(m0 + row) * 2048 + kt * 256 + csrc * 16, Albuf + inst * 1024);
  }
}

// ---------------- QKV GEMM: fp32 A[8192x512] x bf16 Wt[z]^T -> bf16 out[z] ---
// A staged fp32 in LDS (async gload_lds), converted to bf16 fragments at read.
// z<2: out [BH][S][64]; z==2: out transposed [BH][64][S]
__global__ __launch_bounds__(256) void k_gemm_qkv(const float* __restrict__ inQ,
                                                  const float* __restrict__ inK,
                                                  const float* __restrict__ inV,
                                                  const uint16_t* __restrict__ WtBase,
                                                  uint16_t* __restrict__ O0,
                                                  uint16_t* __restrict__ O1,
                                                  uint16_t* __restrict__ O2) {
  __shared__ float Af[2][8192];      // 2 x 32KB fp32 A tile
  __shared__ uint16_t Bs[2][4096];   // 2 x 8KB bf16 B tile
  const int z = blockIdx.z;
  const float* A = (z == 0) ? inQ : (z == 1) ? inK : inV;
  uint16_t* out = (z == 0) ? O0 : (z == 1) ? O1 : O2;
  const uint8_t* Ab = (const uint8_t*)A;
  const uint8_t* Bb = (const uint8_t*)(WtBase + (size_t)z * 262144);
  const int tid = threadIdx.x, lane = tid & 63, wid = tid >> 6;
  const int g = lane >> 4, c16 = lane & 15;
  const int wm = wid & 1, wn = wid >> 1;
  const int m0 = blockIdx.x * 128, n0 = blockIdx.y * 64;
  const int l8 = lane >> 3, cb0 = (lane & 7) << 4;

  f32x4 acc[4][2] = {};

  stageA32(Ab, m0, 0, (uint8_t*)Af[0], wid, lane);
  stageB(Bb, n0, 0, Bs[0], wid, l8, cb0);
  __syncthreads();

  for (int kt = 0; kt < 8; ++kt) {
    const int cur = kt & 1;
    if (kt < 7) {
      stageA32(Ab, m0, kt + 1, (uint8_t*)Af[cur ^ 1], wid, lane);
      stageB(Bb, n0, kt + 1, Bs[cur ^ 1], wid, l8, cb0);
    }
    const uint8_t* Ac = (const uint8_t*)Af[cur];
    const uint16_t* Bc = Bs[cur];
#pragma unroll
    for (int ks = 0; ks < 2; ++ks) {
      bf16x8 af[4], bfr[2];
#pragma unroll
      for (int mi = 0; mi < 4; ++mi) {
        int row = wm * 64 + mi * 16 + c16;
        int r15 = row & 15;
        const uint8_t* rb = Ac + row * 256;
        int c0 = ks * 8 + g * 2;
        f32x4 lo = *(const f32x4*)(rb + ((c0 ^ r15) << 4));
        f32x4 hi = *(const f32x4*)(rb + (((c0 + 1) ^ r15) << 4));
        u32x4 w;
        w[0] = cvtpk(lo[0], lo[1]);
        w[1] = cvtpk(lo[2], lo[3]);
        w[2] = cvtpk(hi[0], hi[1]);
        w[3] = cvtpk(hi[2], hi[3]);
        af[mi] = __builtin_bit_cast(bf16x8, w);
      }
      int cb = ks * 64 + (g << 4);
#pragma unroll
      for (int ni = 0; ni < 2; ++ni) bfr[ni] = ldsfrag(Bc, wn * 32 + ni * 16 + c16, cb);
#pragma unroll
      for (int mi = 0; mi < 4; ++mi)
#pragma unroll
        for (int ni = 0; ni < 2; ++ni)
          acc[mi][ni] = MFMA(af[mi], bfr[ni], acc[mi][ni]);
    }
    __syncthreads();
  }

  const int lm = g * 4;
  if (z != 2) {
#pragma unroll
    for (int mi = 0; mi < 4; ++mi)
#pragma unroll
      for (int ni = 0; ni < 2; ++ni)
#pragma unroll
        for (int r = 0; r < 4; ++r) {
          int m = m0 + wm * 64 + mi * 16 + lm + r;
          int n = n0 + wn * 32 + ni * 16 + c16;
          size_t a = (size_t)((m >> 11) * 8 + (n >> 6)) * 131072 + (size_t)(m & 2047) * 64 + (n & 63);
          out[a] = f2b(acc[mi][ni][r]);
        }
  } else {
#pragma unroll
    for (int mi = 0; mi < 4; ++mi)
#pragma unroll
      for (int ni = 0; ni < 2; ++ni) {
        int m = m0 + wm * 64 + mi * 16 + lm;
        int n = n0 + wn * 32 + ni * 16 + c16;
        u16x4 w;
#pragma unroll
        for (int r = 0; r < 4; ++r) w[r] = f2b(acc[mi][ni][r]);
        size_t a = (size_t)((m >> 11) * 8 + (n >> 6)) * 131072 + (size_t)(n & 63) * 2048 + (m & 2047);
        *(u16x4*)(out + a) = w;
      }
  }
}

// ---------------- FC GEMM: bf16 C[8192x512] = Ctx bf16 x WtF^T ----------------
__global__ __launch_bounds__(256) void k_gemm_fc(const uint16_t* __restrict__ A,
                                                 const uint16_t* __restrict__ Bt,
                                                 uint16_t* __restrict__ out) {
  __shared__ uint16_t As[2][8192];
  __shared__ uint16_t Bs[2][4096];
  const int tid = threadIdx.x, lane = tid & 63, wid = tid >> 6;
  const int g = lane >> 4, c16 = lane & 15;
  const int wm = wid & 1, wn = wid >> 1;
  const int m0 = blockIdx.x * 128, n0 = blockIdx.y * 64;
  const uint8_t* Ab = (const uint8_t*)A;
  const uint8_t* Bb = (const uint8_t*)Bt;
  const int l8 = lane >> 3, cb0 = (lane & 7) << 4;

  f32x4 acc[4][2] = {};

  stage_gemm(Ab, Bb, m0, n0, 0, As[0], Bs[0], wid, l8, cb0);
  __syncthreads();

  for (int kt = 0; kt < 8; ++kt) {
    const int cur = kt & 1;
    if (kt < 7)
      stage_gemm(Ab, Bb, m0, n0, kt + 1, As[cur ^ 1], Bs[cur ^ 1], wid, l8, cb0);
    const uint16_t* Ac = As[cur];
    const uint16_t* Bc = Bs[cur];
#pragma unroll
    for (int ks = 0; ks < 2; ++ks) {
      int cb = ks * 64 + (g << 4);
      bf16x8 af[4], bfr[2];
#pragma unroll
      for (int mi = 0; mi < 4; ++mi) af[mi] = ldsfrag(Ac, wm * 64 + mi * 16 + c16, cb);
#pragma unroll
      for (int ni = 0; ni < 2; ++ni) bfr[ni] = ldsfrag(Bc, wn * 32 + ni * 16 + c16, cb);
#pragma unroll
      for (int mi = 0; mi < 4; ++mi)
#pragma unroll
        for (int ni = 0; ni < 2; ++ni)
          acc[mi][ni] = MFMA(af[mi], bfr[ni], acc[mi][ni]);
    }
    __syncthreads();
  }

  const int lm = g * 4;
#pragma unroll
  for (int mi = 0; mi < 4; ++mi)
#pragma unroll
    for (int ni = 0; ni < 2; ++ni)
#pragma unroll
      for (int r = 0; r < 4; ++r) {
        int m = m0 + wm * 64 + mi * 16 + lm + r;
        int n = n0 + wn * 32 + ni * 16 + c16;
        out[(size_t)m * 512 + n] = f2b(acc[mi][ni][r]);
      }
}

// ---------------- attention staging helpers ----------------
DEV void stageK(const uint8_t* kb, int kt, uint16_t* Ks, int wid, int l8, int cb0) {
#pragma unroll
  for (int i = 0; i < 2; ++i) {
    int inst = wid + i * 4;
    int rho = inst * 8 + l8;
    int f = rho >> 4, g2 = (rho >> 2) & 3, r = rho & 3;
    int s_loc = ((f & 1) << 5) | (g2 << 3) | ((f >> 1) << 2) | r;
    int cbs = cb0 ^ ((rho & 7) << 4);
    gload16(kb + (size_t)(kt * 64 + s_loc) * 128 + cbs, (uint8_t*)Ks + inst * 1024);
  }
}
DEV void stageV(const uint8_t* vb, int kt, uint16_t* Vs, int wid, int l8, int cb0) {
#pragma unroll
  for (int i = 0; i < 2; ++i) {
    int inst = wid + i * 4;
    int row = inst * 8 + l8;
    int cbs = cb0 ^ ((row & 7) << 4);
    gload16(vb + (size_t)row * 4096 + (size_t)kt * 128 + cbs, (uint8_t*)Vs + inst * 1024);
  }
}

// ---------------- Flash attention, causal, QBLK=64, dbuf K/V, Q in regs ------
// R11 configuration (measured best ~38us): 1024 blocks @ 4/CU, balanced remap.
// Shift-free softmax p=exp2(s); row-sum via ones-MFMA.
__global__ __launch_bounds__(256) void k_attn(const uint16_t* __restrict__ qg,
                                              const uint16_t* __restrict__ kg,
                                              const uint16_t* __restrict__ vtg,
                                              uint16_t* __restrict__ ctxg) {
  const int x = blockIdx.x, bh = blockIdx.y;
  const int gx = (x & 1) ? (x >> 1) : 31 - (x >> 1);
  const int qi = ((bh >> 3) & 1) ? 31 - gx : gx;

  const int tid = threadIdx.x, lane = tid & 63, wid = tid >> 6;
  const int g = lane >> 4, qcol = lane & 15;
  __shared__ uint16_t smem[4 * 4096];  // K0 | K1 | V0 | V1 (8KB each)
  const uint8_t* qb = (const uint8_t*)(qg + (size_t)bh * 131072);
  const uint8_t* kb = (const uint8_t*)(kg + (size_t)bh * 131072);
  const uint8_t* vb = (const uint8_t*)(vtg + (size_t)bh * 131072);
  const int l8 = lane >> 3, cb0 = (lane & 7) << 4;
  const int qrow_w = qi * 64 + wid * 16;  // wave's first q row

  // Q fragments straight from global (L2-resident)
  bf16x8 qf[2];
  {
    const uint8_t* qrow = qb + (size_t)(qrow_w + qcol) * 128;
    qf[0] = *(const bf16x8*)(qrow + (g << 4));
    qf[1] = *(const bf16x8*)(qrow + 64 + (g << 4));
  }

  stageK(kb, 0, smem, wid, l8, cb0);
  stageV(vb, 0, smem + 8192, wid, l8, cb0);
  __syncthreads();

  // all-ones bf16 A-fragment for the row-sum MFMA
  bf16x8 ones;
#pragma unroll
  for (int j = 0; j < 8; ++j) ones[j] = (short)0x3F80;

  f32x4 oacc[4] = {};
  f32x4 lacc = {};
  const int nkt = qi + 1;

  for (int kt = 0; kt < nkt; ++kt) {
    const int cur = kt & 1;
    if (kt + 1 < nkt) {
      stageK(kb, kt + 1, smem + ((cur ^ 1) << 12), wid, l8, cb0);
      stageV(vb, kt + 1, smem + 8192 + ((cur ^ 1) << 12), wid, l8, cb0);
    }
    const uint16_t* Kc = smem + (cur << 12);
    const uint16_t* Vc = smem + 8192 + (cur << 12);

    // S^T = K * Q^T  (rows: permuted s, cols: q)
    f32x4 sacc[4] = {};
#pragma unroll
    for (int ks2 = 0; ks2 < 2; ++ks2) {
      int cb = ks2 * 64 + (g << 4);
#pragma unroll
      for (int sf = 0; sf < 4; ++sf) {
        bf16x8 kf = ldsfrag(Kc, sf * 16 + qcol, cb);
        sacc[sf] = MFMA(kf, qf[ks2], sacc[sf]);
      }
    }

    // causal mask (only the diagonal tile)
    if (kt * 64 + 63 > qrow_w) {
      int q_glob = qrow_w + qcol;
#pragma unroll
      for (int sf = 0; sf < 4; ++sf)
#pragma unroll
        for (int r = 0; r < 4; ++r) {
          int s_glob = kt * 64 + (((sf & 1) << 5) | (g << 3) | ((sf >> 1) << 2) | r);
          if (s_glob > q_glob) sacc[sf][r] = -1e30f;
        }
    }

    // p = exp2(s); shift-free (cancels in O/l)
    float p[4][4];
#pragma unroll
    for (int sf = 0; sf < 4; ++sf)
#pragma unroll
      for (int r = 0; r < 4; ++r) p[sf][r] = __builtin_amdgcn_exp2f(sacc[sf][r]);

    // O^T += V^T * P^T ; l += ones * P^T (row-sum on the matrix pipe)
#pragma unroll
    for (int ks = 0; ks < 2; ++ks) {
      u32x4 tv;
      tv[0] = cvtpk(p[ks][0], p[ks][1]);
      tv[1] = cvtpk(p[ks][2], p[ks][3]);
      tv[2] = cvtpk(p[2 + ks][0], p[2 + ks][1]);
      tv[3] = cvtpk(p[2 + ks][2], p[2 + ks][3]);
      bf16x8 pb = __builtin_bit_cast(bf16x8, tv);
      lacc = MFMA(ones, pb, lacc);
#pragma unroll
      for (int dkf = 0; dkf < 4; ++dkf) {
        bf16x8 vf = ldsfrag(Vc, dkf * 16 + qcol, ks * 64 + (g << 4));
        oacc[dkf] = MFMA(vf, pb, oacc[dkf]);
      }
    }
    __syncthreads();
  }

  // epilogue: transpose O^T -> O via per-wave LDS region, then coalesced store
  uint16_t* Os = smem + wid * 1024;  // 2KB per wave (reuses K buffers)
  {
    float iv = 1.f / lacc[0];
    int q_l = qcol;
#pragma unroll
    for (int dkf = 0; dkf < 4; ++dkf) {
      u16x4 w;
#pragma unroll
      for (int r = 0; r < 4; ++r) w[r] = f2b(oacc[dkf][r] * iv);
      int dkb = dkf * 32 + g * 8;
      int bo = q_l * 128 + (dkb ^ ((q_l & 7) << 4));
      *(u16x4*)((uint8_t*)Os + bo) = w;
    }
  }
  __syncthreads();
  const int bb = bh >> 3, hh = bh & 7;
#pragma unroll
  for (int j = 0; j < 2; ++j) {
    int lin = j * 1024 + lane * 16;
    int q_l = lin >> 7;
    int cb = lin & 127;
    int bo = q_l * 128 + (cb ^ ((q_l & 7) << 4));
    bf16x8 val = *(const bf16x8*)((const uint8_t*)(smem + wid * 1024) + bo);
    size_t ga = (size_t)(bb * 2048 + qrow_w + q_l) * 512 + hh * 64 + (cb >> 1);
    *(bf16x8*)(ctxg + ga) = val;
  }
}

// ---------------- residual + LayerNorm (fc in bf16) ----------------
__global__ __launch_bounds__(256) void k_ln(const uint16_t* __restrict__ fc,
                                            const float* __restrict__ resid,
                                            const float* __restrict__ gamma,
                                            const float* __restrict__ beta,
                                            float* __restrict__ out) {
  int row = blockIdx.x * 4 + (threadIdx.x >> 6);
  int lane = threadIdx.x & 63;
  const uint16_t* fr = fc + (size_t)row * 512 + lane * 8;
  const float* rr = resid + (size_t)row * 512 + lane * 8;
  u16x8 fv = *(const u16x8*)fr;
  f32x4 c = *(const f32x4*)rr;
  f32x4 d = *(const f32x4*)(rr + 4);
  float y[8];
#pragma unroll
  for (int j = 0; j < 4; ++j) { y[j] = b2f(fv[j]) + c[j]; y[4 + j] = b2f(fv[4 + j]) + d[j]; }
  float s = 0.f, s2 = 0.f;
#pragma unroll
  for (int j = 0; j < 8; ++j) { s += y[j]; s2 = fmaf(y[j], y[j], s2); }
#pragma unroll
  for (int off = 1; off < 64; off <<= 1) {
    s += __shfl_xor(s, off);
    s2 += __shfl_xor(s2, off);
  }
  float mean = s * (1.f / 512.f);
  float var = s2 * (1.f / 512.f) - mean * mean;
  float rstd = rsqrtf(var + 1e-5f);
  f32x4 o0, o1;
#pragma unroll
  for (int j = 0; j < 4; ++j) {
    o0[j] = (y[j] - mean) * rstd * gamma[lane * 8 + j] + beta[lane * 8 + j];
    o1[j] = (y[4 + j] - mean) * rstd * gamma[lane * 8 + 4 + j] + beta[lane * 8 + 4 + j];
  }
  float* op = out + (size_t)row * 512 + lane * 8;
  *(f32x4*)op = o0;
  *(f32x4*)(op + 4) = o1;
}

extern "C" void kernel_launch(void* const* d_in, const int* in_sizes, int n_in,
                              void* d_out, int out_size, void* d_ws, size_t ws_size,
                              hipStream_t stream) {
  const float* inQ = (const float*)d_in[0];
  const float* inK = (const float*)d_in[1];
  const float* inV = (const float*)d_in[2];
  const float* Wq = (const float*)d_in[4];
  const float* Wk = (const float*)d_in[5];
  const float* Wv = (const float*)d_in[6];
  const float* Wfc = (const float*)d_in[7];
  const float* gamma = (const float*)d_in[8];
  const float* beta = (const float*)d_in[9];
  uint8_t* ws = (uint8_t*)d_ws;
  const size_t MB = 1048576;

  uint16_t* Wt  = (uint16_t*)(ws + 0);          // 4 x 512 KB
  uint16_t* Qb  = (uint16_t*)(ws + 2 * MB);     // [32][2048][64] bf16 (8 MB)
  uint16_t* Kb  = (uint16_t*)(ws + 10 * MB);
  uint16_t* Vtb = (uint16_t*)(ws + 18 * MB);    // [32][64][2048]
  uint16_t* Ctx = (uint16_t*)(ws + 26 * MB);    // [8192][512] bf16
  uint16_t* Fc  = (uint16_t*)(ws + 34 * MB);    // [8192][512] bf16
  float* out = (float*)d_out;

  dim3 b256(256);
  dim3 tb(32, 8), tg4(16, 16, 4);
  // fold attention scale * log2(e) into W_Q
  k_wtrans4<<<tg4, tb, 0, stream>>>(Wq, Wk, Wv, Wfc, Wt, 0.18033688011112042f);

  dim3 gq(64, 8, 3);
  k_gemm_qkv<<<gq, b256, 0, stream>>>(inQ, inK, inV, Wt, Qb, Kb, Vtb);

  dim3 ag(32, 32);
  k_attn<<<ag, b256, 0, stream>>>(Qb, Kb, Vtb, Ctx);

  dim3 gg(64, 8);
  k_gemm_fc<<<gg, b256, 0, stream>>>(Ctx, Wt + 3 * 262144, Fc);
  k_ln<<<2048, b256, 0, stream>>>(Fc, inQ, gamma, beta, out);
}

// Round 15
// 88.445 us; speedup vs baseline: 2.1448x; 1.0343x over previous
//
#include <hip/hip_runtime.h>
#include <hip/hip_bf16.h>
#include <stdint.h>

#define DEV __device__ __forceinline__

using f32x4  = __attribute__((ext_vector_type(4))) float;
using bf16x8 = __attribute__((ext_vector_type(8))) short;
using u16x4  = __attribute__((ext_vector_type(4))) unsigned short;
using u16x8  = __attribute__((ext_vector_type(8))) unsigned short;
using u32x4  = __attribute__((ext_vector_type(4))) uint32_t;

DEV uint16_t f2b(float f) {
  uint32_t u = __builtin_bit_cast(uint32_t, f);
  uint32_t r = u + 0x7FFFu + ((u >> 16) & 1u);
  return (uint16_t)(r >> 16);
}
DEV float b2f(uint16_t h) {
  return __builtin_bit_cast(float, (uint32_t)h << 16);
}

DEV uint32_t cvtpk(float lo, float hi) {
  uint32_t r;
  asm("v_cvt_pk_bf16_f32 %0, %1, %2" : "=v"(r) : "v"(lo), "v"(hi));
  return r;
}

DEV void gload16(const void* g, void* l) {
  __builtin_amdgcn_global_load_lds((__attribute__((address_space(1))) void*)g,
                                   (__attribute__((address_space(3))) void*)l,
                                   16, 0, 0);
}

// bf16 LDS tiles have 128-byte rows; XOR-swizzle bits 4..6 by (row&7).
DEV bf16x8 ldsfrag(const uint16_t* base, int row, int cb) {
  int b = row * 128 + (cb ^ ((row & 7) << 4));
  return *(const bf16x8*)((const uint8_t*)base + b);
}

DEV f32x4 MFMA(bf16x8 a, bf16x8 b, f32x4 c) {
  return __builtin_amdgcn_mfma_f32_16x16x32_bf16(a, b, c, 0, 0, 0);
}

// ---------------- all 4 weights: W [k][n] fp32 -> Wt [n][k] bf16 (x scale) ----
__global__ void k_wtrans4(const float* __restrict__ W0, const float* __restrict__ W1,
                          const float* __restrict__ W2, const float* __restrict__ W3,
                          uint16_t* __restrict__ WtBase, float scale0) {
  __shared__ float t[32][33];
  const int z = blockIdx.z;
  const float* W = (z == 0) ? W0 : (z == 1) ? W1 : (z == 2) ? W2 : W3;
  const float scale = (z == 0) ? scale0 : 1.0f;
  uint16_t* Wt = WtBase + (size_t)z * 262144;
  int tx = threadIdx.x, ty = threadIdx.y;
  int n0 = blockIdx.x * 32, k0 = blockIdx.y * 32;
#pragma unroll
  for (int i = 0; i < 4; ++i)
    t[ty + 8 * i][tx] = W[(size_t)(k0 + ty + 8 * i) * 512 + n0 + tx];
  __syncthreads();
#pragma unroll
  for (int i = 0; i < 4; ++i)
    Wt[(size_t)(n0 + ty + 8 * i) * 512 + k0 + tx] = f2b(t[tx][ty + 8 * i] * scale);
}

// ---------------- bf16 GEMM staging helper (128B rows) ----------------
DEV void stage_gemm(const uint8_t* Ab, const uint8_t* Bb, int m0, int n0, int kt,
                    uint16_t* As, uint16_t* Bs, int wid, int l8, int cb0) {
#pragma unroll
  for (int i = 0; i < 4; ++i) {
    int inst = wid + i * 4;
    int row = inst * 8 + l8;
    int cbs = cb0 ^ ((row & 7) << 4);
    gload16(Ab + (size_t)(m0 + row) * 1024 + kt * 128 + cbs, (uint8_t*)As + inst * 1024);
  }
#pragma unroll
  for (int i = 0; i < 2; ++i) {
    int inst = wid + i * 4;
    int row = inst * 8 + l8;
    int cbs = cb0 ^ ((row & 7) << 4);
    gload16(Bb + (size_t)(n0 + row) * 1024 + kt * 128 + cbs, (uint8_t*)Bs + inst * 1024);
  }
}

// ---------------- fp32 A staging, BK=32: [128 rows][128B], chunk ^= row&7 ----
// Linear LDS dest (4 passes x 4KB) + inverse-swizzled global source.
DEV void stageA32(const uint8_t* Ab, int m0, int kt, uint8_t* Albuf, int wid, int lane) {
#pragma unroll
  for (int i = 0; i < 4; ++i) {
    int row = i * 32 + wid * 8 + (lane >> 3);
    int cg = (lane & 7) ^ (row & 7);
    gload16(Ab + (size_t)(m0 + row) * 2048 + kt * 128 + cg * 16, Albuf + i * 4096 + wid * 1024);
  }
}

// ---------------- bf16 B staging, BK=32: [64 rows][64B], chunk ^= row&3 ------
DEV void stageB32(const uint8_t* Bb, int n0, int kt, uint8_t* Bbuf, int wid, int lane) {
  int row = wid * 16 + (lane >> 2);
  int cg = (lane & 3) ^ (row & 3);
  gload16(Bb + (size_t)(n0 + row) * 1024 + kt * 64 + cg * 16, Bbuf + wid * 1024);
}

// ---------------- QKV GEMM: fp32 A[8192x512] x bf16 Wt[z]^T -> bf16 out[z] ---
// BK=32: LDS 40KB -> 4 blocks/CU. A staged fp32, converted at fragment read.
// z<2: out [BH][S][64]; z==2: out transposed [BH][64][S]
__global__ __launch_bounds__(256) void k_gemm_qkv(const float* __restrict__ inQ,
                                                  const float* __restrict__ inK,
                                                  const float* __restrict__ inV,
                                                  const uint16_t* __restrict__ WtBase,
                                                  uint16_t* __restrict__ O0,
                                                  uint16_t* __restrict__ O1,
                                                  uint16_t* __restrict__ O2) {
  __shared__ float Af[2][4096];      // 2 x 16KB fp32 A tile (128 x 32)
  __shared__ uint16_t Bs[2][2048];   // 2 x 4KB bf16 B tile (64 x 32)
  const int z = blockIdx.z;
  const float* A = (z == 0) ? inQ : (z == 1) ? inK : inV;
  uint16_t* out = (z == 0) ? O0 : (z == 1) ? O1 : O2;
  const uint8_t* Ab = (const uint8_t*)A;
  const uint8_t* Bb = (const uint8_t*)(WtBase + (size_t)z * 262144);
  const int tid = threadIdx.x, lane = tid & 63, wid = tid >> 6;
  const int g = lane >> 4, c16 = lane & 15;
  const int wm = wid & 1, wn = wid >> 1;
  const int m0 = blockIdx.x * 128, n0 = blockIdx.y * 64;

  f32x4 acc[4][2] = {};

  stageA32(Ab, m0, 0, (uint8_t*)Af[0], wid, lane);
  stageB32(Bb, n0, 0, (uint8_t*)Bs[0], wid, lane);
  __syncthreads();

  for (int kt = 0; kt < 16; ++kt) {
    const int cur = kt & 1;
    if (kt < 15) {
      stageA32(Ab, m0, kt + 1, (uint8_t*)Af[cur ^ 1], wid, lane);
      stageB32(Bb, n0, kt + 1, (uint8_t*)Bs[cur ^ 1], wid, lane);
    }
    const uint8_t* Ac = (const uint8_t*)Af[cur];
    const uint8_t* Bc = (const uint8_t*)Bs[cur];
    bf16x8 af[4], bfr[2];
#pragma unroll
    for (int mi = 0; mi < 4; ++mi) {
      int row = wm * 64 + mi * 16 + c16;
      int r7 = row & 7;
      const uint8_t* rb = Ac + row * 128;
      f32x4 lo = *(const f32x4*)(rb + (((2 * g) ^ r7) << 4));
      f32x4 hi = *(const f32x4*)(rb + (((2 * g + 1) ^ r7) << 4));
      u32x4 w;
      w[0] = cvtpk(lo[0], lo[1]);
      w[1] = cvtpk(lo[2], lo[3]);
      w[2] = cvtpk(hi[0], hi[1]);
      w[3] = cvtpk(hi[2], hi[3]);
      af[mi] = __builtin_bit_cast(bf16x8, w);
    }
#pragma unroll
    for (int ni = 0; ni < 2; ++ni) {
      int row = wn * 32 + ni * 16 + c16;
      bfr[ni] = *(const bf16x8*)(Bc + row * 64 + ((g ^ (row & 3)) << 4));
    }
#pragma unroll
    for (int mi = 0; mi < 4; ++mi)
#pragma unroll
      for (int ni = 0; ni < 2; ++ni)
        acc[mi][ni] = MFMA(af[mi], bfr[ni], acc[mi][ni]);
    __syncthreads();
  }

  const int lm = g * 4;
  if (z != 2) {
#pragma unroll
    for (int mi = 0; mi < 4; ++mi)
#pragma unroll
      for (int ni = 0; ni < 2; ++ni)
#pragma unroll
        for (int r = 0; r < 4; ++r) {
          int m = m0 + wm * 64 + mi * 16 + lm + r;
          int n = n0 + wn * 32 + ni * 16 + c16;
          size_t a = (size_t)((m >> 11) * 8 + (n >> 6)) * 131072 + (size_t)(m & 2047) * 64 + (n & 63);
          out[a] = f2b(acc[mi][ni][r]);
        }
  } else {
#pragma unroll
    for (int mi = 0; mi < 4; ++mi)
#pragma unroll
      for (int ni = 0; ni < 2; ++ni) {
        int m = m0 + wm * 64 + mi * 16 + lm;
        int n = n0 + wn * 32 + ni * 16 + c16;
        u16x4 w;
#pragma unroll
        for (int r = 0; r < 4; ++r) w[r] = f2b(acc[mi][ni][r]);
        size_t a = (size_t)((m >> 11) * 8 + (n >> 6)) * 131072 + (size_t)(n & 63) * 2048 + (m & 2047);
        *(u16x4*)(out + a) = w;
      }
  }
}

// ---------------- FC GEMM: bf16 C[8192x512] = Ctx bf16 x WtF^T ----------------
__global__ __launch_bounds__(256) void k_gemm_fc(const uint16_t* __restrict__ A,
                                                 const uint16_t* __restrict__ Bt,
                                                 uint16_t* __restrict__ out) {
  __shared__ uint16_t As[2][8192];
  __shared__ uint16_t Bs[2][4096];
  const int tid = threadIdx.x, lane = tid & 63, wid = tid >> 6;
  const int g = lane >> 4, c16 = lane & 15;
  const int wm = wid & 1, wn = wid >> 1;
  const int m0 = blockIdx.x * 128, n0 = blockIdx.y * 64;
  const uint8_t* Ab = (const uint8_t*)A;
  const uint8_t* Bb = (const uint8_t*)Bt;
  const int l8 = lane >> 3, cb0 = (lane & 7) << 4;

  f32x4 acc[4][2] = {};

  stage_gemm(Ab, Bb, m0, n0, 0, As[0], Bs[0], wid, l8, cb0);
  __syncthreads();

  for (int kt = 0; kt < 8; ++kt) {
    const int cur = kt & 1;
    if (kt < 7)
      stage_gemm(Ab, Bb, m0, n0, kt + 1, As[cur ^ 1], Bs[cur ^ 1], wid, l8, cb0);
    const uint16_t* Ac = As[cur];
    const uint16_t* Bc = Bs[cur];
#pragma unroll
    for (int ks = 0; ks < 2; ++ks) {
      int cb = ks * 64 + (g << 4);
      bf16x8 af[4], bfr[2];
#pragma unroll
      for (int mi = 0; mi < 4; ++mi) af[mi] = ldsfrag(Ac, wm * 64 + mi * 16 + c16, cb);
#pragma unroll
      for (int ni = 0; ni < 2; ++ni) bfr[ni] = ldsfrag(Bc, wn * 32 + ni * 16 + c16, cb);
#pragma unroll
      for (int mi = 0; mi < 4; ++mi)
#pragma unroll
        for (int ni = 0; ni < 2; ++ni)
          acc[mi][ni] = MFMA(af[mi], bfr[ni], acc[mi][ni]);
    }
    __syncthreads();
  }

  const int lm = g * 4;
#pragma unroll
  for (int mi = 0; mi < 4; ++mi)
#pragma unroll
    for (int ni = 0; ni < 2; ++ni)
#pragma unroll
      for (int r = 0; r < 4; ++r) {
        int m = m0 + wm * 64 + mi * 16 + lm + r;
        int n = n0 + wn * 32 + ni * 16 + c16;
        out[(size_t)m * 512 + n] = f2b(acc[mi][ni][r]);
      }
}

// ---------------- attention staging helpers ----------------
DEV void stageK(const uint8_t* kb, int kt, uint16_t* Ks, int wid, int l8, int cb0) {
#pragma unroll
  for (int i = 0; i < 2; ++i) {
    int inst = wid + i * 4;
    int rho = inst * 8 + l8;
    int f = rho >> 4, g2 = (rho >> 2) & 3, r = rho & 3;
    int s_loc = ((f & 1) << 5) | (g2 << 3) | ((f >> 1) << 2) | r;
    int cbs = cb0 ^ ((rho & 7) << 4);
    gload16(kb + (size_t)(kt * 64 + s_loc) * 128 + cbs, (uint8_t*)Ks + inst * 1024);
  }
}
DEV void stageV(const uint8_t* vb, int kt, uint16_t* Vs, int wid, int l8, int cb0) {
#pragma unroll
  for (int i = 0; i < 2; ++i) {
    int inst = wid + i * 4;
    int row = inst * 8 + l8;
    int cbs = cb0 ^ ((row & 7) << 4);
    gload16(vb + (size_t)row * 4096 + (size_t)kt * 128 + cbs, (uint8_t*)Vs + inst * 1024);
  }
}

// ---------------- Flash attention, causal, QBLK=64, dbuf K/V, Q in regs ------
// R11 configuration (measured best): 1024 blocks @ 4/CU, balanced remap.
// Shift-free softmax p=exp2(s); row-sum via ones-MFMA.
__global__ __launch_bounds__(256) void k_attn(const uint16_t* __restrict__ qg,
                                              const uint16_t* __restrict__ kg,
                                              const uint16_t* __restrict__ vtg,
                                              uint16_t* __restrict__ ctxg) {
  const int x = blockIdx.x, bh = blockIdx.y;
  const int gx = (x & 1) ? (x >> 1) : 31 - (x >> 1);
  const int qi = ((bh >> 3) & 1) ? 31 - gx : gx;

  const int tid = threadIdx.x, lane = tid & 63, wid = tid >> 6;
  const int g = lane >> 4, qcol = lane & 15;
  __shared__ uint16_t smem[4 * 4096];  // K0 | K1 | V0 | V1 (8KB each)
  const uint8_t* qb = (const uint8_t*)(qg + (size_t)bh * 131072);
  const uint8_t* kb = (const uint8_t*)(kg + (size_t)bh * 131072);
  const uint8_t* vb = (const uint8_t*)(vtg + (size_t)bh * 131072);
  const int l8 = lane >> 3, cb0 = (lane & 7) << 4;
  const int qrow_w = qi * 64 + wid * 16;  // wave's first q row

  // Q fragments straight from global (L2-resident)
  bf16x8 qf[2];
  {
    const uint8_t* qrow = qb + (size_t)(qrow_w + qcol) * 128;
    qf[0] = *(const bf16x8*)(qrow + (g << 4));
    qf[1] = *(const bf16x8*)(qrow + 64 + (g << 4));
  }

  stageK(kb, 0, smem, wid, l8, cb0);
  stageV(vb, 0, smem + 8192, wid, l8, cb0);
  __syncthreads();

  // all-ones bf16 A-fragment for the row-sum MFMA
  bf16x8 ones;
#pragma unroll
  for (int j = 0; j < 8; ++j) ones[j] = (short)0x3F80;

  f32x4 oacc[4] = {};
  f32x4 lacc = {};
  const int nkt = qi + 1;

  for (int kt = 0; kt < nkt; ++kt) {
    const int cur = kt & 1;
    if (kt + 1 < nkt) {
      stageK(kb, kt + 1, smem + ((cur ^ 1) << 12), wid, l8, cb0);
      stageV(vb, kt + 1, smem + 8192 + ((cur ^ 1) << 12), wid, l8, cb0);
    }
    const uint16_t* Kc = smem + (cur << 12);
    const uint16_t* Vc = smem + 8192 + (cur << 12);

    // S^T = K * Q^T  (rows: permuted s, cols: q)
    f32x4 sacc[4] = {};
#pragma unroll
    for (int ks2 = 0; ks2 < 2; ++ks2) {
      int cb = ks2 * 64 + (g << 4);
#pragma unroll
      for (int sf = 0; sf < 4; ++sf) {
        bf16x8 kf = ldsfrag(Kc, sf * 16 + qcol, cb);
        sacc[sf] = MFMA(kf, qf[ks2], sacc[sf]);
      }
    }

    // causal mask (only the diagonal tile)
    if (kt * 64 + 63 > qrow_w) {
      int q_glob = qrow_w + qcol;
#pragma unroll
      for (int sf = 0; sf < 4; ++sf)
#pragma unroll
        for (int r = 0; r < 4; ++r) {
          int s_glob = kt * 64 + (((sf & 1) << 5) | (g << 3) | ((sf >> 1) << 2) | r);
          if (s_glob > q_glob) sacc[sf][r] = -1e30f;
        }
    }

    // p = exp2(s); shift-free (cancels in O/l)
    float p[4][4];
#pragma unroll
    for (int sf = 0; sf < 4; ++sf)
#pragma unroll
      for (int r = 0; r < 4; ++r) p[sf][r] = __builtin_amdgcn_exp2f(sacc[sf][r]);

    // O^T += V^T * P^T ; l += ones * P^T (row-sum on the matrix pipe)
#pragma unroll
    for (int ks = 0; ks < 2; ++ks) {
      u32x4 tv;
      tv[0] = cvtpk(p[ks][0], p[ks][1]);
      tv[1] = cvtpk(p[ks][2], p[ks][3]);
      tv[2] = cvtpk(p[2 + ks][0], p[2 + ks][1]);
      tv[3] = cvtpk(p[2 + ks][2], p[2 + ks][3]);
      bf16x8 pb = __builtin_bit_cast(bf16x8, tv);
      lacc = MFMA(ones, pb, lacc);
#pragma unroll
      for (int dkf = 0; dkf < 4; ++dkf) {
        bf16x8 vf = ldsfrag(Vc, dkf * 16 + qcol, ks * 64 + (g << 4));
        oacc[dkf] = MFMA(vf, pb, oacc[dkf]);
      }
    }
    __syncthreads();
  }

  // epilogue: transpose O^T -> O via per-wave LDS region, then coalesced store
  uint16_t* Os = smem + wid * 1024;  // 2KB per wave (reuses K buffers)
  {
    float iv = 1.f / lacc[0];
    int q_l = qcol;
#pragma unroll
    for (int dkf = 0; dkf < 4; ++dkf) {
      u16x4 w;
#pragma unroll
      for (int r = 0; r < 4; ++r) w[r] = f2b(oacc[dkf][r] * iv);
      int dkb = dkf * 32 + g * 8;
      int bo = q_l * 128 + (dkb ^ ((q_l & 7) << 4));
      *(u16x4*)((uint8_t*)Os + bo) = w;
    }
  }
  __syncthreads();
  const int bb = bh >> 3, hh = bh & 7;
#pragma unroll
  for (int j = 0; j < 2; ++j) {
    int lin = j * 1024 + lane * 16;
    int q_l = lin >> 7;
    int cb = lin & 127;
    int bo = q_l * 128 + (cb ^ ((q_l & 7) << 4));
    bf16x8 val = *(const bf16x8*)((const uint8_t*)(smem + wid * 1024) + bo);
    size_t ga = (size_t)(bb * 2048 + qrow_w + q_l) * 512 + hh * 64 + (cb >> 1);
    *(bf16x8*)(ctxg + ga) = val;
  }
}

// ---------------- residual + LayerNorm (fc in bf16) ----------------
__global__ __launch_bounds__(256) void k_ln(const uint16_t* __restrict__ fc,
                                            const float* __restrict__ resid,
                                            const float* __restrict__ gamma,
                                            const float* __restrict__ beta,
                                            float* __restrict__ out) {
  int row = blockIdx.x * 4 + (threadIdx.x >> 6);
  int lane = threadIdx.x & 63;
  const uint16_t* fr = fc + (size_t)row * 512 + lane * 8;
  const float* rr = resid + (size_t)row * 512 + lane * 8;
  u16x8 fv = *(const u16x8*)fr;
  f32x4 c = *(const f32x4*)rr;
  f32x4 d = *(const f32x4*)(rr + 4);
  float y[8];
#pragma unroll
  for (int j = 0; j < 4; ++j) { y[j] = b2f(fv[j]) + c[j]; y[4 + j] = b2f(fv[4 + j]) + d[j]; }
  float s = 0.f, s2 = 0.f;
#pragma unroll
  for (int j = 0; j < 8; ++j) { s += y[j]; s2 = fmaf(y[j], y[j], s2); }
#pragma unroll
  for (int off = 1; off < 64; off <<= 1) {
    s += __shfl_xor(s, off);
    s2 += __shfl_xor(s2, off);
  }
  float mean = s * (1.f / 512.f);
  float var = s2 * (1.f / 512.f) - mean * mean;
  float rstd = rsqrtf(var + 1e-5f);
  f32x4 o0, o1;
#pragma unroll
  for (int j = 0; j < 4; ++j) {
    o0[j] = (y[j] - mean) * rstd * gamma[lane * 8 + j] + beta[lane * 8 + j];
    o1[j] = (y[4 + j] - mean) * rstd * gamma[lane * 8 + 4 + j] + beta[lane * 8 + 4 + j];
  }
  float* op = out + (size_t)row * 512 + lane * 8;
  *(f32x4*)op = o0;
  *(f32x4*)(op + 4) = o1;
}

extern "C" void kernel_launch(void* const* d_in, const int* in_sizes, int n_in,
                              void* d_out, int out_size, void* d_ws, size_t ws_size,
                              hipStream_t stream) {
  const float* inQ = (const float*)d_in[0];
  const float* inK = (const float*)d_in[1];
  const float* inV = (const float*)d_in[2];
  const float* Wq = (const float*)d_in[4];
  const float* Wk = (const float*)d_in[5];
  const float* Wv = (const float*)d_in[6];
  const float* Wfc = (const float*)d_in[7];
  const float* gamma = (const float*)d_in[8];
  const float* beta = (const float*)d_in[9];
  uint8_t* ws = (uint8_t*)d_ws;
  const size_t MB = 1048576;

  uint16_t* Wt  = (uint16_t*)(ws + 0);          // 4 x 512 KB
  uint16_t* Qb  = (uint16_t*)(ws + 2 * MB);     // [32][2048][64] bf16 (8 MB)
  uint16_t* Kb  = (uint16_t*)(ws + 10 * MB);
  uint16_t* Vtb = (uint16_t*)(ws + 18 * MB);    // [32][64][2048]
  uint16_t* Ctx = (uint16_t*)(ws + 26 * MB);    // [8192][512] bf16
  uint16_t* Fc  = (uint16_t*)(ws + 34 * MB);    // [8192][512] bf16
  float* out = (float*)d_out;

  dim3 b256(256);
  dim3 tb(32, 8), tg4(16, 16, 4);
  // fold attention scale * log2(e) into W_Q
  k_wtrans4<<<tg4, tb, 0, stream>>>(Wq, Wk, Wv, Wfc, Wt, 0.18033688011112042f);

  dim3 gq(64, 8, 3);
  k_gemm_qkv<<<gq, b256, 0, stream>>>(inQ, inK, inV, Wt, Qb, Kb, Vtb);

  dim3 ag(32, 32);
  k_attn<<<ag, b256, 0, stream>>>(Qb, Kb, Vtb, Ctx);

  dim3 gg(64, 8);
  k_gemm_fc<<<gg, b256, 0, stream>>>(Ctx, Wt + 3 * 262144, Fc);
  k_ln<<<2048, b256, 0, stream>>>(Fc, inQ, gamma, beta, out);
}